// Round 4
// baseline (2182.704 us; speedup 1.0000x reference)
//
#include <hip/hip_runtime.h>
#include <hip/hip_bf16.h>
#include <math.h>

#define BATCH 256
#define TSTEPS 1024
#define DIN 64
#define HID 100
#define MB 16               // batch columns per WG (dense MFMA N)
#define NWG (BATCH / MB)    // 16 workgroups
#define WAVES 7
#define BLOCK (WAVES * 64)  // 448
#define TPW 4               // M-tiles per wave: 28 tiles cover 26 real (M=416 interleaved)
#define HROW 136            // Hl row stride (shorts): 272B -> +4 banks/row, conflict-free
#define L2E 1.4426950408889634f

typedef __attribute__((ext_vector_type(8))) short bf16x8;  // 8 bf16 (4 VGPRs)
typedef __attribute__((ext_vector_type(4))) float f32x4;

__device__ __forceinline__ short f2bf(float f) {
    return (short)__bfloat16_as_ushort(__float2bfloat16(f));  // RNE
}
__device__ __forceinline__ float x2f(float x) {              // exp2, 1 trans op
#if __has_builtin(__builtin_amdgcn_exp2f)
    return __builtin_amdgcn_exp2f(x);
#else
    return exp2f(x);
#endif
}
__device__ __forceinline__ float rcpf_(float x) { return __builtin_amdgcn_rcpf(x); }

// M-rows are gate-interleaved: row R = 4*unit + gate  (gate 0..3 = i,f,g,o).
// A-frag (lane view): row = l&15, k = 32*kt + 8*(l>>4) + j.
// C/D (verified m89/m91): col = l&15 (batch), row = 4*(l>>4) + reg
//   -> lane's 4 acc regs = (i,f,g,o) of unit u = 4*tile + (l>>4), batch = l&15.
__global__ __launch_bounds__(BLOCK, 1)
void lstm_mfma_kernel(const float* __restrict__ x, const float* __restrict__ h0,
                      const float* __restrict__ c0, const float* __restrict__ W_ih,
                      const float* __restrict__ W_hh, const float* __restrict__ b_ih,
                      const float* __restrict__ b_hh, const float* __restrict__ W_fc,
                      const float* __restrict__ b_fc, float* __restrict__ out)
{
    __shared__ short Hl[MB * HROW];          // h state, bf16, cols 100..127 = 0
    __shared__ float red[WAVES * 4][MB];     // FC-head reduce

    const int tid = threadIdx.x;
    const int w   = tid >> 6;
    const int l   = tid & 63;
    const int lb  = l & 15;                  // batch col / A row-in-tile
    const int lg  = l >> 4;                  // k-group / C row-group
    const int bg0 = blockIdx.x * MB;

    // ---------- A fragments (weights, bf16, log2e folded: i,f,o -> -L2E; g -> +2*L2E) ----
    bf16x8 Ah[TPW][4];
    bf16x8 Ax[TPW][2];
    f32x4  bias[TPW];
    float  cc[TPW];
    int    uc[TPW];
    #pragma unroll
    for (int ti = 0; ti < TPW; ++ti) {
        const int tg = w * TPW + ti;
        const int R  = tg * 16 + lb;
        const int u  = R >> 2;
        const int qg = R & 3;
        const bool val = (u < HID);
        const float scl = (qg == 2) ? 2.0f * L2E : -L2E;
        const float* wr  = W_hh + (size_t)(qg * HID + (val ? u : 0)) * HID;
        const float* wr2 = W_ih + (size_t)(qg * HID + (val ? u : 0)) * DIN;
        #pragma unroll
        for (int kt = 0; kt < 4; ++kt)
            #pragma unroll
            for (int j = 0; j < 8; ++j) {
                int k = kt * 32 + lg * 8 + j;
                float v = (val && k < HID) ? wr[k] : 0.f;
                Ah[ti][kt][j] = f2bf(v * scl);
            }
        #pragma unroll
        for (int kt = 0; kt < 2; ++kt)
            #pragma unroll
            for (int j = 0; j < 8; ++j) {
                float v = val ? wr2[kt * 32 + lg * 8 + j] : 0.f;
                Ax[ti][kt][j] = f2bf(v * scl);
            }
        // epilogue-side (C-layout) unit for this lane/tile
        const int u_c = tg * 4 + lg;
        uc[ti] = u_c;
        const bool vcv = (u_c < HID);
        f32x4 bb;
        #pragma unroll
        for (int r = 0; r < 4; ++r) {
            float s2 = (r == 2) ? 2.0f * L2E : -L2E;
            bb[r] = vcv ? (b_ih[r * HID + u_c] + b_hh[r * HID + u_c]) * s2 : 0.f;
        }
        bias[ti] = bb;
        cc[ti] = vcv ? c0[(size_t)(bg0 + lb) * HID + u_c] : 0.f;
    }

    // ---------- init H (bf16), zero pad cols ----------
    for (int idx = tid; idx < MB * 128; idx += BLOCK) {
        int bb2 = idx >> 7, k = idx & 127;
        float v = (k < HID) ? h0[(size_t)(bg0 + bb2) * HID + k] : 0.f;
        Hl[bb2 * HROW + k] = f2bf(v);
    }
    __syncthreads();

    const float* xp = x + (size_t)(bg0 + lb) * TSTEPS * DIN + lg * 8;
    const short* hb = Hl + lb * HROW + lg * 8;
    short*       hw = Hl + lb * HROW;

    float hlast[TPW];
    #pragma unroll
    for (int ti = 0; ti < TPW; ++ti) hlast[ti] = 0.f;

    for (int t = 0; t < TSTEPS; ++t) {
        // B fragments for h (read before barrier; writes happen after it)
        bf16x8 Bh0 = *(const bf16x8*)(hb);
        bf16x8 Bh1 = *(const bf16x8*)(hb + 32);
        bf16x8 Bh2 = *(const bf16x8*)(hb + 64);
        bf16x8 Bh3 = *(const bf16x8*)(hb + 96);
        __syncthreads();   // barrier A: all waves' H reads complete

        // x loads issued here: drain only at barrier B -> latency hidden under MFMAs
        const float4* p0 = (const float4*)(xp + (size_t)t * DIN);
        const float4* p1 = (const float4*)(xp + (size_t)t * DIN + 32);
        float4 va = p0[0];
        float4 vb = p0[1];
        float4 vc4 = p1[0];
        float4 vd = p1[1];

        f32x4 acc[TPW];
        #pragma unroll
        for (int ti = 0; ti < TPW; ++ti) acc[ti] = bias[ti];   // bias as C-in: free
        #pragma unroll
        for (int ti = 0; ti < TPW; ++ti) {
            acc[ti] = __builtin_amdgcn_mfma_f32_16x16x32_bf16(Ah[ti][0], Bh0, acc[ti], 0, 0, 0);
            acc[ti] = __builtin_amdgcn_mfma_f32_16x16x32_bf16(Ah[ti][1], Bh1, acc[ti], 0, 0, 0);
            acc[ti] = __builtin_amdgcn_mfma_f32_16x16x32_bf16(Ah[ti][2], Bh2, acc[ti], 0, 0, 0);
            acc[ti] = __builtin_amdgcn_mfma_f32_16x16x32_bf16(Ah[ti][3], Bh3, acc[ti], 0, 0, 0);
        }
        bf16x8 Bx0, Bx1;
        Bx0[0]=f2bf(va.x); Bx0[1]=f2bf(va.y); Bx0[2]=f2bf(va.z); Bx0[3]=f2bf(va.w);
        Bx0[4]=f2bf(vb.x); Bx0[5]=f2bf(vb.y); Bx0[6]=f2bf(vb.z); Bx0[7]=f2bf(vb.w);
        Bx1[0]=f2bf(vc4.x); Bx1[1]=f2bf(vc4.y); Bx1[2]=f2bf(vc4.z); Bx1[3]=f2bf(vc4.w);
        Bx1[4]=f2bf(vd.x); Bx1[5]=f2bf(vd.y); Bx1[6]=f2bf(vd.z); Bx1[7]=f2bf(vd.w);
        #pragma unroll
        for (int ti = 0; ti < TPW; ++ti) {
            acc[ti] = __builtin_amdgcn_mfma_f32_16x16x32_bf16(Ax[ti][0], Bx0, acc[ti], 0, 0, 0);
            acc[ti] = __builtin_amdgcn_mfma_f32_16x16x32_bf16(Ax[ti][1], Bx1, acc[ti], 0, 0, 0);
        }

        // epilogue: acc = (-zi*L2E, -zf*L2E, +2*zg*L2E, -zo*L2E)
        #pragma unroll
        for (int ti = 0; ti < TPW; ++ti) {
            float Ei = x2f(acc[ti][0]);          // e^{-zi}
            float Ef = x2f(acc[ti][1]);          // e^{-zf}
            float G  = x2f(acc[ti][2]);          // e^{+2 zg}
            float Eo = x2f(acc[ti][3]);          // e^{-zo}
            float P  = (1.f + Ei) * (1.f + G);
            float D  = (1.f + Ef) * P;
            // c' = sigmoid(zf)*c + sigmoid(zi)*tanh(zg)  (single shared reciprocal)
            float num = fmaf(cc[ti], P, (G - 1.f) * (1.f + Ef));
            float c2  = num * rcpf_(D);
            cc[ti] = c2;
            float C2 = x2f(fminf(c2, 15.f) * (2.0f * L2E));   // e^{2c}, overflow-guarded
            float hv = (C2 - 1.f) * rcpf_((1.f + Eo) * (C2 + 1.f)); // sigmoid(zo)*tanh(c)
            hlast[ti] = hv;
            if (uc[ti] < HID) hw[uc[ti]] = f2bf(hv);
        }
        __syncthreads();   // barrier B: h(t+1) visible (also drains x loads)
    }

    // ---------- FC head: out[b] = h_T . W_fc + b_fc ----------
    float part = 0.f;
    #pragma unroll
    for (int ti = 0; ti < TPW; ++ti)
        if (uc[ti] < HID) part += hlast[ti] * W_fc[uc[ti]];
    red[w * 4 + lg][lb] = part;
    __syncthreads();
    if (tid < MB) {
        float s = b_fc[0];
        #pragma unroll
        for (int i = 0; i < WAVES * 4; ++i) s += red[i][tid];
        out[bg0 + tid] = s;
    }
}

extern "C" void kernel_launch(void* const* d_in, const int* in_sizes, int n_in,
                              void* d_out, int out_size, void* d_ws, size_t ws_size,
                              hipStream_t stream) {
    const float* x    = (const float*)d_in[0];
    const float* h0   = (const float*)d_in[1];
    const float* c0   = (const float*)d_in[2];
    const float* W_ih = (const float*)d_in[3];
    const float* W_hh = (const float*)d_in[4];
    const float* b_ih = (const float*)d_in[5];
    const float* b_hh = (const float*)d_in[6];
    const float* W_fc = (const float*)d_in[7];
    const float* b_fc = (const float*)d_in[8];
    float* out = (float*)d_out;

    lstm_mfma_kernel<<<dim3(NWG), dim3(BLOCK), 0, stream>>>(
        x, h0, c0, W_ih, W_hh, b_ih, b_hh, W_fc, b_fc, out);
}

// Round 5
// 1058.550 us; speedup vs baseline: 2.0620x; 2.0620x over previous
//
#include <hip/hip_runtime.h>
#include <hip/hip_bf16.h>
#include <math.h>

#define BATCH 256
#define TSTEPS 1024
#define DIN 64
#define HID 100
#define MB 16               // batch columns per WG (MFMA N)
#define NWG (BATCH / MB)    // 16 workgroups
#define WAVES 7
#define BLOCK (WAVES * 64)  // 448
#define TPW 4               // M-tiles per wave: 28 tiles cover 26 real (M=416 interleaved)
#define HROW 136            // Hl row stride (shorts): 272B, 16B-aligned, ~2-way banks
#define L2E 1.4426950408889634f

typedef __attribute__((ext_vector_type(8))) short bf16x8;  // 8 bf16 (4 VGPRs)
typedef __attribute__((ext_vector_type(4))) float f32x4;

static __device__ __forceinline__ short f2bf(float f) {
    return (short)__bfloat16_as_ushort(__float2bfloat16(f));  // RNE
}
static __device__ __forceinline__ float x2f(float x) {
#if __has_builtin(__builtin_amdgcn_exp2f)
    return __builtin_amdgcn_exp2f(x);
#else
    return exp2f(x);
#endif
}
static __device__ __forceinline__ float rcpf_(float x) { return __builtin_amdgcn_rcpf(x); }

// M-rows gate-interleaved: row R = 4*unit + gate (0..3 = i,f,g,o).
// A-frag: row = l&15, k = 32*kt + 8*(l>>4) + j.
// C/D (m89/m91): col = l&15 (batch), row = 4*(l>>4) + reg
//   -> lane's 4 acc regs = (i,f,g,o) of unit uc = 4*tile + (l>>4), batch = l&15.
__global__ __launch_bounds__(BLOCK, 1)
void lstm_mfma_kernel(const float* __restrict__ x, const float* __restrict__ h0,
                      const float* __restrict__ c0, const float* __restrict__ W_ih,
                      const float* __restrict__ W_hh, const float* __restrict__ b_ih,
                      const float* __restrict__ b_hh, const float* __restrict__ W_fc,
                      const float* __restrict__ b_fc, float* __restrict__ out)
{
    __shared__ short Hl[2][MB * HROW];       // double-buffered h state (bf16)
    __shared__ float red[WAVES * 4][MB];     // FC-head reduce

    const int tid = threadIdx.x;
    const int w   = tid >> 6;
    const int l   = tid & 63;
    const int lb  = l & 15;                  // batch col / A row-in-tile
    const int lg  = l >> 4;                  // k-group / C row-group
    const int bg0 = blockIdx.x * MB;

    // ---------- A fragments (weights, bf16; log2e folded: i,f,o -> -L2E; g -> +2*L2E) ----
    bf16x8 Ah[TPW][4];
    bf16x8 Ax[TPW][2];
    f32x4  bias[TPW];
    float  cc[TPW];
    int    uc[TPW];
    #pragma unroll
    for (int ti = 0; ti < TPW; ++ti) {
        const int tg = w * TPW + ti;
        const int R  = tg * 16 + lb;
        const int u  = R >> 2;
        const int qg = R & 3;
        const bool val = (u < HID);
        const float scl = (qg == 2) ? 2.0f * L2E : -L2E;
        const float* wr  = W_hh + (size_t)(qg * HID + (val ? u : 0)) * HID;
        const float* wr2 = W_ih + (size_t)(qg * HID + (val ? u : 0)) * DIN;
        #pragma unroll
        for (int kt = 0; kt < 4; ++kt)
            #pragma unroll
            for (int j = 0; j < 8; ++j) {
                int k = kt * 32 + lg * 8 + j;
                float v = (val && k < HID) ? wr[k] : 0.f;
                Ah[ti][kt][j] = f2bf(v * scl);
            }
        #pragma unroll
        for (int kt = 0; kt < 2; ++kt)
            #pragma unroll
            for (int j = 0; j < 8; ++j) {
                float v = val ? wr2[kt * 32 + lg * 8 + j] : 0.f;
                Ax[ti][kt][j] = f2bf(v * scl);
            }
        const int u_c = tg * 4 + lg;         // epilogue-side (C-layout) unit
        uc[ti] = u_c;
        const bool vcv = (u_c < HID);
        f32x4 bb;
        #pragma unroll
        for (int r = 0; r < 4; ++r) {
            float s2 = (r == 2) ? 2.0f * L2E : -L2E;
            bb[r] = vcv ? (b_ih[r * HID + u_c] + b_hh[r * HID + u_c]) * s2 : 0.f;
        }
        bias[ti] = bb;
        cc[ti] = vcv ? c0[(size_t)(bg0 + lb) * HID + u_c] : 0.f;
    }

    // ---------- init H: buf0 = h0 (pad cols 0), buf1 = 0 (real cols overwritten at t=0) ---
    for (int idx = tid; idx < MB * 128; idx += BLOCK) {
        int bb2 = idx >> 7, k = idx & 127;
        float v = (k < HID) ? h0[(size_t)(bg0 + bb2) * HID + k] : 0.f;
        Hl[0][bb2 * HROW + k] = f2bf(v);
        Hl[1][bb2 * HROW + k] = 0;
    }
    __syncthreads();

    const float* xbase = x + (size_t)(bg0 + lb) * TSTEPS * DIN + lg * 8;

    float hlast[TPW];
    #pragma unroll
    for (int ti = 0; ti < TPW; ++ti) hlast[ti] = 0.f;

    // prime x(0)
    float4 va = *(const float4*)(xbase);
    float4 vb = *(const float4*)(xbase + 4);
    float4 vc4 = *(const float4*)(xbase + 32);
    float4 vd = *(const float4*)(xbase + 36);
    float4 na, nb, nc, nd;

#define LSTM_STEP(T_, CUR_, XA, XB, XC, XD, NA_, NB_, NC_, ND_)                              \
    {                                                                                        \
        const short* hb = &Hl[CUR_][lb * HROW + lg * 8];                                     \
        bf16x8 Bh0 = *(const bf16x8*)(hb);                                                   \
        bf16x8 Bh1 = *(const bf16x8*)(hb + 32);                                              \
        bf16x8 Bh2 = *(const bf16x8*)(hb + 64);                                              \
        bf16x8 Bh3 = *(const bf16x8*)(hb + 96);                                              \
        const int tn_ = ((T_) + 1 < TSTEPS) ? (T_) + 1 : (T_);                               \
        const float* xq_ = xbase + (size_t)tn_ * DIN;                                        \
        NA_ = *(const float4*)(xq_);                                                         \
        NB_ = *(const float4*)(xq_ + 4);                                                     \
        NC_ = *(const float4*)(xq_ + 32);                                                    \
        ND_ = *(const float4*)(xq_ + 36);                                                    \
        f32x4 acc[TPW];                                                                      \
        _Pragma("unroll") for (int ti = 0; ti < TPW; ++ti) acc[ti] = bias[ti];               \
        _Pragma("unroll") for (int ti = 0; ti < TPW; ++ti) {                                 \
            acc[ti] = __builtin_amdgcn_mfma_f32_16x16x32_bf16(Ah[ti][0], Bh0, acc[ti], 0, 0, 0); \
            acc[ti] = __builtin_amdgcn_mfma_f32_16x16x32_bf16(Ah[ti][1], Bh1, acc[ti], 0, 0, 0); \
            acc[ti] = __builtin_amdgcn_mfma_f32_16x16x32_bf16(Ah[ti][2], Bh2, acc[ti], 0, 0, 0); \
            acc[ti] = __builtin_amdgcn_mfma_f32_16x16x32_bf16(Ah[ti][3], Bh3, acc[ti], 0, 0, 0); \
        }                                                                                    \
        bf16x8 Bx0, Bx1;                                                                     \
        Bx0[0]=f2bf(XA.x); Bx0[1]=f2bf(XA.y); Bx0[2]=f2bf(XA.z); Bx0[3]=f2bf(XA.w);          \
        Bx0[4]=f2bf(XB.x); Bx0[5]=f2bf(XB.y); Bx0[6]=f2bf(XB.z); Bx0[7]=f2bf(XB.w);          \
        Bx1[0]=f2bf(XC.x); Bx1[1]=f2bf(XC.y); Bx1[2]=f2bf(XC.z); Bx1[3]=f2bf(XC.w);          \
        Bx1[4]=f2bf(XD.x); Bx1[5]=f2bf(XD.y); Bx1[6]=f2bf(XD.z); Bx1[7]=f2bf(XD.w);          \
        _Pragma("unroll") for (int ti = 0; ti < TPW; ++ti) {                                 \
            acc[ti] = __builtin_amdgcn_mfma_f32_16x16x32_bf16(Ax[ti][0], Bx0, acc[ti], 0, 0, 0); \
            acc[ti] = __builtin_amdgcn_mfma_f32_16x16x32_bf16(Ax[ti][1], Bx1, acc[ti], 0, 0, 0); \
        }                                                                                    \
        short* hw = &Hl[CUR_ ^ 1][lb * HROW];                                                \
        _Pragma("unroll") for (int ti = 0; ti < TPW; ++ti) {                                 \
            if (uc[ti] < HID) {  /* wave-uniform per tile: pad tiles skip all trans */       \
                float Ei = x2f(acc[ti][0]);                                                  \
                float Ef = x2f(acc[ti][1]);                                                  \
                float G  = x2f(acc[ti][2]);                                                  \
                float Eo = x2f(acc[ti][3]);                                                  \
                float P  = (1.f + Ei) * (1.f + G);                                           \
                float D  = (1.f + Ef) * P;                                                   \
                float num = fmaf(cc[ti], P, (G - 1.f) * (1.f + Ef));                         \
                float c2  = num * rcpf_(D);                                                  \
                cc[ti] = c2;                                                                 \
                float C2 = x2f(fminf(c2, 15.f) * (2.0f * L2E));                              \
                float hv = (C2 - 1.f) * rcpf_((1.f + Eo) * (C2 + 1.f));                      \
                hlast[ti] = hv;                                                              \
                hw[uc[ti]] = f2bf(hv);                                                       \
            }                                                                                \
        }                                                                                    \
        __syncthreads();                                                                     \
    }

    for (int t = 0; t < TSTEPS; t += 2) {
        LSTM_STEP(t,     0, va, vb, vc4, vd,  na, nb, nc, nd)
        LSTM_STEP(t + 1, 1, na, nb, nc, nd,  va, vb, vc4, vd)
    }
#undef LSTM_STEP

    // ---------- FC head: out[b] = h_T . W_fc + b_fc ----------
    float part = 0.f;
    #pragma unroll
    for (int ti = 0; ti < TPW; ++ti)
        if (uc[ti] < HID) part += hlast[ti] * W_fc[uc[ti]];
    red[w * 4 + lg][lb] = part;
    __syncthreads();
    if (tid < MB) {
        float s = b_fc[0];
        #pragma unroll
        for (int i = 0; i < WAVES * 4; ++i) s += red[i][tid];
        out[bg0 + tid] = s;
    }
}

extern "C" void kernel_launch(void* const* d_in, const int* in_sizes, int n_in,
                              void* d_out, int out_size, void* d_ws, size_t ws_size,
                              hipStream_t stream) {
    const float* x    = (const float*)d_in[0];
    const float* h0   = (const float*)d_in[1];
    const float* c0   = (const float*)d_in[2];
    const float* W_ih = (const float*)d_in[3];
    const float* W_hh = (const float*)d_in[4];
    const float* b_ih = (const float*)d_in[5];
    const float* b_hh = (const float*)d_in[6];
    const float* W_fc = (const float*)d_in[7];
    const float* b_fc = (const float*)d_in[8];
    float* out = (float*)d_out;

    lstm_mfma_kernel<<<dim3(NWG), dim3(BLOCK), 0, stream>>>(
        x, h0, c0, W_ih, W_hh, b_ih, b_hh, W_fc, b_fc, out);
}

// Round 6
// 899.387 us; speedup vs baseline: 2.4269x; 1.1770x over previous
//
#include <hip/hip_runtime.h>
#include <math.h>

#define BATCH 256
#define TSTEPS 1024
#define DIN 64
#define HID 100
#define BLOCK 832     // 800 gate threads (2 per gate row), 13 waves
#define XT 32         // timesteps per x LDS tile
#define HBUF_U32 56   // 112 f16 per h buffer (100 real + pad zeros)

typedef _Float16 f16;
typedef f16 f16x2 __attribute__((ext_vector_type(2)));
typedef unsigned int u32;

union UH { u32 u; f16x2 h; };

static __device__ __forceinline__ float dot2u(u32 a, u32 b, float c) {
    UH ua, ub; ua.u = a; ub.u = b;
#if __has_builtin(__builtin_amdgcn_fdot2)
    return __builtin_amdgcn_fdot2(ua.h, ub.h, c, false);   // v_dot2_f32_f16
#else
    return c + (float)ua.h[0] * (float)ub.h[0] + (float)ua.h[1] * (float)ub.h[1];
#endif
}
static __device__ __forceinline__ u32 pkf(float a, float b) {
    UH r; r.h[0] = (f16)a; r.h[1] = (f16)b; return r.u;
}
static __device__ __forceinline__ float rcpf_(float x) { return __builtin_amdgcn_rcpf(x); }

// Thread layout: tid = 8*n + 2*q + p   (n=unit, q=gate i/f/g/o, p=k-half)
// p=0: W_hh k 0..51 (window halves 0..55, w[52..55]=0), W_ih k 0..31
// p=1: W_hh k 52..99 (window halves 48..103, w outside [52,99] = 0), W_ih k 32..63
__global__ __launch_bounds__(BLOCK, 1)
void lstm_dot2_kernel(const float* __restrict__ x, const float* __restrict__ h0,
                      const float* __restrict__ c0, const float* __restrict__ W_ih,
                      const float* __restrict__ W_hh, const float* __restrict__ b_ih,
                      const float* __restrict__ b_hh, const float* __restrict__ W_fc,
                      const float* __restrict__ b_fc, float* __restrict__ out)
{
    __shared__ u32 h_lds[2][HBUF_U32];        // f16x2-packed hidden state, double-buffered
    __shared__ u32 x_lds[XT * DIN / 2];       // f16x2-packed x tile (4 KB)
    __shared__ float red[HID];

    const int tid = threadIdx.x;
    const int b   = blockIdx.x;
    const int p   = tid & 1;
    const int gq  = tid >> 1;
    const int q   = gq & 3;                   // gate
    const int n   = gq >> 2;                  // unit 0..103 (>=100 pad)
    const int nl  = (n < HID) ? n : (HID - 1);
    const int gl  = q * HID + nl;
    const int cb  = p * 48;                   // h-window half-base

    // ---- packed f16 weights: 28 + 16 u32 per thread ----
    u32 whh[28];
    #pragma unroll
    for (int m = 0; m < 28; ++m) {
        const int k0 = cb + 2 * m, k1 = k0 + 1;
        const bool v0 = p ? (k0 >= 52 && k0 < HID) : (k0 < 52);
        const bool v1 = p ? (k1 >= 52 && k1 < HID) : (k1 < 52);
        whh[m] = pkf(v0 ? W_hh[gl * HID + k0] : 0.f, v1 ? W_hh[gl * HID + k1] : 0.f);
    }
    u32 wih[16];
    #pragma unroll
    for (int m = 0; m < 16; ++m) {
        const int k0 = p * 32 + 2 * m;
        wih[m] = pkf(W_ih[gl * DIN + k0], W_ih[gl * DIN + k0 + 1]);
    }

    const float bias = (p == 0) ? (b_ih[gl] + b_hh[gl]) : 0.f;

    // activation constants: q==2 -> tanh, else sigmoid
    const float mQ = (q == 2) ?  2.f : -1.f;
    const float aQ = (q == 2) ?  1.f :  0.f;
    const float bQ = (q == 2) ? -2.f :  1.f;

    // ---- init h (f16 packed), c ----
    if (tid < HBUF_U32) {
        const int k = 2 * tid;
        float v0 = (k     < HID) ? h0[b * HID + k]     : 0.f;
        float v1 = (k + 1 < HID) ? h0[b * HID + k + 1] : 0.f;
        h_lds[0][tid] = pkf(v0, v1);
        h_lds[1][tid] = 0;                    // pad halves 100..111 must stay 0
    }
    float c = 0.f;
    if ((tid & 7) == 0) c = c0[b * HID + nl];
    float hlast = 0.f;
    __syncthreads();

    for (int tt = 0; tt < TSTEPS; tt += XT) {
        if (tid < 512) {                      // stage 32 steps of x, f32 -> f16x2
            float4 v = reinterpret_cast<const float4*>(
                x + (size_t)b * TSTEPS * DIN + (size_t)tt * DIN)[tid];
            x_lds[2 * tid]     = pkf(v.x, v.y);
            x_lds[2 * tid + 1] = pkf(v.z, v.w);
        }
        __syncthreads();

        #pragma unroll 2
        for (int t2 = 0; t2 < XT; ++t2) {
            const int cur = (tt + t2) & 1;

            float a0 = 0.f, a1 = 0.f, a2 = 0.f, a3 = 0.f;
            const uint4* hp = reinterpret_cast<const uint4*>(&h_lds[cur][p * 24]);
            #pragma unroll
            for (int r = 0; r < 7; ++r) {     // 28 dot2 = 56 h-MACs
                uint4 hv = hp[r];             // broadcast read: conflict-free
                a0 = dot2u(whh[4*r+0], hv.x, a0);
                a1 = dot2u(whh[4*r+1], hv.y, a1);
                a2 = dot2u(whh[4*r+2], hv.z, a2);
                a3 = dot2u(whh[4*r+3], hv.w, a3);
            }
            const uint4* xp = reinterpret_cast<const uint4*>(&x_lds[t2 * 32 + p * 16]);
            #pragma unroll
            for (int r = 0; r < 4; ++r) {     // 16 dot2 = 32 x-MACs
                uint4 xv = xp[r];
                a0 = dot2u(wih[4*r+0], xv.x, a0);
                a1 = dot2u(wih[4*r+1], xv.y, a1);
                a2 = dot2u(wih[4*r+2], xv.z, a2);
                a3 = dot2u(wih[4*r+3], xv.w, a3);
            }
            float sum = ((a0 + a1) + (a2 + a3)) + bias;
            float z = sum + __shfl_xor(sum, 1);     // k-pair reduce

            float e = __expf(mQ * z);
            float s = rcpf_(1.f + e);
            float a = fmaf(bQ, s, aQ);              // sigmoid or tanh per q

            float fv = __shfl_down(a, 2);
            float gv = __shfl_down(a, 4);
            float ov = __shfl_down(a, 6);
            if ((tid & 7) == 0) {
                c = fmaf(fv, c, a * gv);            // c = f*c + i*g
                float e2 = __expf(c + c);
                float th = fmaf(-2.f, rcpf_(1.f + e2), 1.f);   // tanh(c)
                hlast = ov * th;
                if (n < HID)
                    reinterpret_cast<f16*>(&h_lds[cur ^ 1][0])[n] = (f16)hlast;
            }
            __syncthreads();
        }
    }

    // ---- FC head ----
    if ((tid & 7) == 0 && n < HID) red[n] = hlast * W_fc[n];
    __syncthreads();
    if (tid == 0) {
        float s = b_fc[0];
        #pragma unroll 4
        for (int i = 0; i < HID; ++i) s += red[i];
        out[b] = s;
    }
}

extern "C" void kernel_launch(void* const* d_in, const int* in_sizes, int n_in,
                              void* d_out, int out_size, void* d_ws, size_t ws_size,
                              hipStream_t stream) {
    const float* x    = (const float*)d_in[0];
    const float* h0   = (const float*)d_in[1];
    const float* c0   = (const float*)d_in[2];
    const float* W_ih = (const float*)d_in[3];
    const float* W_hh = (const float*)d_in[4];
    const float* b_ih = (const float*)d_in[5];
    const float* b_hh = (const float*)d_in[6];
    const float* W_fc = (const float*)d_in[7];
    const float* b_fc = (const float*)d_in[8];
    float* out = (float*)d_out;

    lstm_dot2_kernel<<<dim3(BATCH), dim3(BLOCK), 0, stream>>>(
        x, h0, c0, W_ih, W_hh, b_ih, b_hh, W_fc, b_fc, out);
}